// Round 15
// baseline (146.921 us; speedup 1.0000x reference)
//
#include <hip/hip_runtime.h>
#include <math.h>

#define NPTS  80
#define HALF  40
#define NDEL  16
#define NBATCH 256
#define NTH   256
#define PIX   (NPTS * NPTS)              // 6400
#define QUADS (PIX / 4)                  // 1600
#define SLICES (NDEL * PIX)              // 102400
#define NSLICE (NBATCH * NDEL)           // 4096
#define TOTAL ((long long)NBATCH * NDEL * PIX)   // 26214400 = out_size (real part only)

// f32 constants with the same bits numpy uses: float32(np.pi), float32(2*np.pi)
static constexpr float PI_F32     = 3.14159265358979323846f;   // -> 3.1415927f
static constexpr float TWO_PI_F32 = 6.28318530717958647692f;   // -> 6.2831855f

// Bit-faithful mirror of the np f32 reference interp:
// t = (xn - x0)/dx; f=floor, c=ceil; lin = ((yc-yf)*xn + yf*xc - yc*xf)/denom
// numpy evaluates each ufunc separately in f32 with NO fma -> contract off.
__device__ __forceinline__ float interp_f32(const float* __restrict__ xs,
                                            const float* __restrict__ ys,
                                            float xn) {
#pragma clang fp contract(off)
    float dx = xs[1] - xs[0];
    float t  = (xn - xs[0]) / dx;
    int f = (int)floorf(t);
    int c = (int)ceilf(t);
    float yf = ys[f], yc = ys[c];
    float xf = xs[f], xc = xs[c];
    bool  same  = (c == f);
    float denom = same ? 1.0f : (xc - xf);
    float p2 = (yc - yf) * xn;     // f32 rounded, numpy order
    float p3 = yf * xc;            // f32 rounded
    float p4 = p2 + p3;            // ((a*b)+(c*d))
    float p5 = yc * xf;            // f32 rounded
    float p6 = p4 - p5;            // (...)-(e*f)
    float lin = p6 / denom;
    return same ? yc : lin;
}

// Per-(d,i,j) precompute, ALL f32 (the np reference is all-f32: round-14's
// f64 kernel scored 0.0371 > round-8's f32 0.0215, eliminating the f64-ref
// theory). ifftshift remap folded in. c4 = {k, w, w_pi, m0+2*m1}.
__global__ void __launch_bounds__(256)
precompute_kernel(const float* __restrict__ thetas,
                  const float* __restrict__ wfs,
                  const float* __restrict__ k2D,
                  const float* __restrict__ theta2D,
                  const float* __restrict__ mask0,
                  const float* __restrict__ mask1,
                  float4* __restrict__ c4) {
    __shared__ float s_th[NTH];
    __shared__ float s_wf[NTH];
    for (int i = threadIdx.x; i < NTH; i += blockDim.x) {
        s_th[i] = thetas[i];
        s_wf[i] = wfs[i];
    }
    __syncthreads();

    int idx = blockIdx.x * blockDim.x + threadIdx.x;
    if (idx >= SLICES) return;

    int d  = idx / PIX;
    int p  = idx - d * PIX;
    int oi = p / NPTS;
    int oj = p - oi * NPTS;
    // ifftshift (even N): out[oi][oj] = in[(oi+N/2)%N][(oj+N/2)%N]
    int si = oi + HALF; if (si >= NPTS) si -= NPTS;
    int sj = oj + HALF; if (sj >= NPTS) sj -= NPTS;
    int src = d * PIX + si * NPTS + sj;

    float k  = k2D[src];
    float th = theta2D[src];
    float m0 = mask0[src];
    float m1 = mask1[src];

    float w = interp_f32(s_th, s_wf, th);

    // np.mod(th + np.pi, 2*np.pi) in f32: np.pi is a WEAK scalar (plain float)
    // so the add stays f32; np.mod for positive args == fmodf (IEEE-exact).
    float thp;
    {
#pragma clang fp contract(off)
        float x = th + PI_F32;             // f32 rounded, same bits as np
        thp = fmodf(x, TWO_PI_F32);        // exact -> identical bits
    }
    float w_pi = interp_f32(s_th, s_wf, thp);

    c4[idx] = make_float4(k, w, w_pi, m0 + 2.0f * m1);
}

// Main kernel: REAL PART ONLY, linear pixel order, out_size == TOTAL
// (validated rounds 4/6/7/8/12). Phase in f32 exactly as np:
// a0 = f32(k * f32(delay - w)); cosf directly on the raw phase — numpy hands
// the same f32 bits to glibc cosf; OCML cosf does its own accurate reduction.
__global__ void __launch_bounds__(256)
tf_real_kernel(const float* __restrict__ delays,
               const float4* __restrict__ c4,
               float* __restrict__ out,
               long long nout) {
    int slice = blockIdx.x;                // = b*NDEL + d
    int d     = slice & (NDEL - 1);
    float delay = delays[slice];           // (B,D,1,1) flat, b-major d-minor
    const float4* C4 = c4 + d * PIX;
    size_t base = (size_t)slice * PIX;

    for (int pq = threadIdx.x; pq < QUADS; pq += blockDim.x) {
        int p0 = pq * 4;
        float re[4];
        #pragma unroll
        for (int u = 0; u < 4; ++u) {
            float4 v = C4[p0 + u];         // {k, w, w_pi, m0+2*m1}
            float m1 = floorf(v.w * 0.5f);
            float m0 = v.w - 2.0f * m1;
            float a0, a1, t0, t1, s;
            {
#pragma clang fp contract(off)
                a0 = v.x * (delay - v.y);  // f32, numpy op order, no fma
                a1 = v.x * (delay - v.z);
            }
            float c0 = cosf(a0);           // OCML, full-range reduction
            float c1 = cosf(a1);
            {
#pragma clang fp contract(off)
                t0 = m0 * c0;              // mirror np complex64 combine
                t1 = m1 * c1;
                s  = t0 + t1;
            }
            re[u] = 0.5f * s;              // *0.5 exact
        }
        size_t o = base + (size_t)p0;
        if ((long long)(o + 4) <= nout) {
            *(float4*)(out + o) = make_float4(re[0], re[1], re[2], re[3]);
        }
    }
}

// Fused fallback (no workspace): identical f32 math, real-only, guarded.
__global__ void __launch_bounds__(256)
tf_fused_kernel(const float* __restrict__ delays,
                const float* __restrict__ thetas,
                const float* __restrict__ wfs,
                const float* __restrict__ k2D,
                const float* __restrict__ theta2D,
                const float* __restrict__ mask0,
                const float* __restrict__ mask1,
                float* __restrict__ out,
                long long nout) {
    __shared__ float s_th[NTH];
    __shared__ float s_wf[NTH];
    for (int i = threadIdx.x; i < NTH; i += blockDim.x) {
        s_th[i] = thetas[i];
        s_wf[i] = wfs[i];
    }
    __syncthreads();

    int slice = blockIdx.x;
    int d     = slice & (NDEL - 1);
    float delay = delays[slice];
    const float* K  = k2D     + d * PIX;
    const float* TH = theta2D + d * PIX;
    const float* M0 = mask0   + d * PIX;
    const float* M1 = mask1   + d * PIX;
    size_t base = (size_t)slice * PIX;

    for (int p = threadIdx.x; p < PIX; p += blockDim.x) {
        int oi = p / NPTS;
        int oj = p - oi * NPTS;
        int si = oi + HALF; if (si >= NPTS) si -= NPTS;
        int sj = oj + HALF; if (sj >= NPTS) sj -= NPTS;
        int src = si * NPTS + sj;

        float k  = K[src];
        float th = TH[src];
        float m0 = M0[src];
        float m1 = M1[src];

        float w = interp_f32(s_th, s_wf, th);
        float thp;
        {
#pragma clang fp contract(off)
            float x = th + PI_F32;
            thp = fmodf(x, TWO_PI_F32);
        }
        float w_pi = interp_f32(s_th, s_wf, thp);

        float a0, a1, t0, t1, s;
        {
#pragma clang fp contract(off)
            a0 = k * (delay - w);
            a1 = k * (delay - w_pi);
        }
        float c0 = cosf(a0);
        float c1 = cosf(a1);
        {
#pragma clang fp contract(off)
            t0 = m0 * c0;
            t1 = m1 * c1;
            s  = t0 + t1;
        }
        float re = 0.5f * s;

        size_t o = base + (size_t)p;
        if ((long long)(o + 1) <= nout) {
            out[o] = re;
        }
    }
}

extern "C" void kernel_launch(void* const* d_in, const int* in_sizes, int n_in,
                              void* d_out, int out_size, void* d_ws, size_t ws_size,
                              hipStream_t stream) {
    const float* delays  = (const float*)d_in[0];  // (256,16,1,1)
    const float* thetas  = (const float*)d_in[1];  // (256,)
    const float* wfs     = (const float*)d_in[2];  // (256,)
    const float* k2D     = (const float*)d_in[3];  // (1,16,80,80)
    const float* theta2D = (const float*)d_in[4];
    const float* mask0   = (const float*)d_in[5];
    const float* mask1   = (const float*)d_in[6];

    long long nout = (long long)out_size;          // f32 element count (== TOTAL)

    size_t need = (size_t)SLICES * sizeof(float4);
    if (d_ws != nullptr && ws_size >= need) {
        float4* c4 = (float4*)d_ws;
        precompute_kernel<<<(SLICES + 255) / 256, 256, 0, stream>>>(
            thetas, wfs, k2D, theta2D, mask0, mask1, c4);
        tf_real_kernel<<<NSLICE, 256, 0, stream>>>(
            delays, c4, (float*)d_out, nout);
    } else {
        tf_fused_kernel<<<NSLICE, 256, 0, stream>>>(
            delays, thetas, wfs, k2D, theta2D, mask0, mask1,
            (float*)d_out, nout);
    }
}